// Round 9
// baseline (397.365 us; speedup 1.0000x reference)
//
#include <hip/hip_runtime.h>
#include <stdint.h>
#include <stddef.h>

#define B_ 2
#define S_ 2048
#define D_ 1024
#define H_ 16
#define HD_ 64
#define FF_ 4096

typedef unsigned short u16;
typedef __attribute__((ext_vector_type(8))) short bf16x8;
typedef __attribute__((ext_vector_type(4))) short bf16x4;
typedef __attribute__((ext_vector_type(4))) float f32x4;

__device__ __forceinline__ u16 f2bf(float f) {
  unsigned u = __float_as_uint(f);
  u += 0x7fffu + ((u >> 16) & 1u);
  return (u16)(u >> 16);
}

__device__ __forceinline__ f32x4 mfma16(bf16x8 a, bf16x8 b, f32x4 c) {
  return __builtin_amdgcn_mfma_f32_16x16x32_bf16(a, b, c, 0, 0, 0);
}

#if defined(__has_builtin)
#if __has_builtin(__builtin_amdgcn_mfma_f32_16x16x16bf16_1k)
#define HAVE_MFMA_1K 1
#endif
#endif

// K=16 MFMA: D[m][n] += sum_k A[m][k]*B[n][k]; A,B = 4 bf16 (2 VGPRs).
__device__ __forceinline__ f32x4 mfma16k16(bf16x4 a, bf16x4 b, f32x4 c) {
#ifdef HAVE_MFMA_1K
  return __builtin_amdgcn_mfma_f32_16x16x16bf16_1k(a, b, c, 0, 0, 0);
#else
  asm("v_mfma_f32_16x16x16_bf16 %0, %1, %2, %0" : "+v"(c) : "v"(a), "v"(b));
  return c;
#endif
}

__device__ __forceinline__ void gload16(const void* g, void* l) {
  __builtin_amdgcn_global_load_lds(
      (const __attribute__((address_space(1))) void*)g,
      (__attribute__((address_space(3))) void*)l, 16, 0, 0);
}

// XCD-aware block swizzle (bijective when gridDim.x % 8 == 0).
__device__ __forceinline__ void swizzle_mn(int& mt, int& nt) {
  int gm = gridDim.x;
  if ((gm & 7) == 0) {
    int bid = blockIdx.y * gm + blockIdx.x;
    int mper = gm >> 3;
    int xcd = bid & 7, idx = bid >> 3;
    mt = xcd * mper + (idx % mper);
    nt = idx / mper;
  } else {
    mt = blockIdx.x;
    nt = blockIdx.y;
  }
}

// ---------------- fused prep: x cvt + all weight transposes ----------------
__global__ __launch_bounds__(256) void prep_kernel(
    const float* __restrict__ x, u16* __restrict__ xb,
    const float* __restrict__ W1, u16* __restrict__ w1T,
    const float* __restrict__ W2, u16* __restrict__ w2T,
    const float* __restrict__ Wq, const float* __restrict__ Wk,
    const float* __restrict__ Wv, const float* __restrict__ Wo,
    u16* __restrict__ wTq, u16* __restrict__ wTk,
    u16* __restrict__ wTv, u16* __restrict__ wTo) {
  int bid = blockIdx.x;
  int tid = threadIdx.x;
  if (bid >= 8192 && bid < 12288) {  // cvt path
    int i = (bid - 8192) * 1024 + tid * 4;
    float4 v = *(const float4*)(x + i);
    ushort4 o = { f2bf(v.x), f2bf(v.y), f2bf(v.z), f2bf(v.w) };
    *(ushort4*)(xb + i) = o;
    return;
  }
  const float* W;
  u16* WT;
  int K, N, k0, n0;
  if (bid < 4096) {
    W = W1; WT = w1T; K = 1024; N = 4096;
    k0 = (bid & 31) * 32; n0 = (bid >> 5) * 32;
  } else if (bid < 8192) {
    int b2 = bid - 4096;
    W = W2; WT = w2T; K = 4096; N = 1024;
    k0 = (b2 >> 5) * 32; n0 = (b2 & 31) * 32;
  } else {
    int t = bid - 12288;
    int z = t >> 10, rr = t & 1023;
    W = z == 0 ? Wq : (z == 1 ? Wk : (z == 2 ? Wv : Wo));
    WT = z == 0 ? wTq : (z == 1 ? wTk : (z == 2 ? wTv : wTo));
    K = 1024; N = 1024;
    k0 = (rr & 31) * 32; n0 = (rr >> 5) * 32;
  }
  __shared__ u16 t[32][33];
  int r = tid >> 3;
  int c = (tid & 7) << 2;
  float4 v = *(const float4*)(W + (size_t)(k0 + r) * N + n0 + c);
  t[r][c + 0] = f2bf(v.x); t[r][c + 1] = f2bf(v.y);
  t[r][c + 2] = f2bf(v.z); t[r][c + 3] = f2bf(v.w);
  __syncthreads();
  ushort4 o;
  o.x = t[c + 0][r]; o.y = t[c + 1][r]; o.z = t[c + 2][r]; o.w = t[c + 3][r];
  *(ushort4*)(WT + (size_t)(n0 + r) * K + k0 + c) = o;
}

// ---------------- GEMM 128x128, out bf16 + relu (+bias)  [ffn1] ------------
__global__ __launch_bounds__(256, 4) void gemm_bt_relu(
    const u16* __restrict__ A, const u16* __restrict__ BT,
    const float* __restrict__ bias, u16* __restrict__ outp,
    int M, int N, int K) {
  __shared__ __align__(16) u16 As[128 * 32];
  __shared__ __align__(16) u16 Bs[128 * 32];
  int tid = threadIdx.x;
  int lane = tid & 63;
  int wave = tid >> 6;
  int quad = lane >> 4;
  int l16 = lane & 15;
  int mt, nt;
  swizzle_mn(mt, nt);
  int m0 = mt * 128;
  int n0 = nt * 128;
  int wm = (wave >> 1) * 64;
  int wn = (wave & 1) * 64;

  f32x4 zero = {0.f, 0.f, 0.f, 0.f};
  f32x4 acc[4][4];
#pragma unroll
  for (int i = 0; i < 4; i++)
#pragma unroll
    for (int j = 0; j < 4; j++) acc[i][j] = zero;

  int c0 = tid, c1 = tid + 256;
  const u16* ga0 = A + (size_t)(m0 + (c0 >> 2)) * K + (c0 & 3) * 8;
  const u16* ga1 = A + (size_t)(m0 + (c1 >> 2)) * K + (c1 & 3) * 8;
  const u16* gb0 = BT + (size_t)(n0 + (c0 >> 2)) * K + (c0 & 3) * 8;
  const u16* gb1 = BT + (size_t)(n0 + (c1 >> 2)) * K + (c1 & 3) * 8;

  for (int k0 = 0; k0 < K; k0 += 32) {
    gload16(ga0 + k0, &As[c0 * 8]);
    gload16(ga1 + k0, &As[c1 * 8]);
    gload16(gb0 + k0, &Bs[c0 * 8]);
    gload16(gb1 + k0, &Bs[c1 * 8]);
    __syncthreads();
    bf16x8 af[4], bfr[4];
#pragma unroll
    for (int i = 0; i < 4; i++)
      af[i] = *(const bf16x8*)&As[(wm + i * 16 + l16) * 32 + quad * 8];
#pragma unroll
    for (int j = 0; j < 4; j++)
      bfr[j] = *(const bf16x8*)&Bs[(wn + j * 16 + l16) * 32 + quad * 8];
#pragma unroll
    for (int i = 0; i < 4; i++)
#pragma unroll
      for (int j = 0; j < 4; j++)
        acc[i][j] = mfma16(af[i], bfr[j], acc[i][j]);
    __syncthreads();
  }

#pragma unroll
  for (int j = 0; j < 4; j++) {
    int gcol = n0 + wn + j * 16 + l16;
    float bv = bias[gcol];
#pragma unroll
    for (int i = 0; i < 4; i++) {
#pragma unroll
      for (int r = 0; r < 4; r++) {
        int grow = m0 + wm + i * 16 + quad * 4 + r;
        float val = acc[i][j][r] + bv;
        outp[(size_t)grow * N + gcol] = f2bf(val > 0.f ? val : 0.f);
      }
    }
  }
}

// ---------------- GEMM 128x128 split-K (up to 4), separate fp32 outputs ----
__global__ __launch_bounds__(256, 4) void gemm_bt_sk4(
    const u16* __restrict__ A, const u16* __restrict__ BT,
    const float* __restrict__ bias,
    float* __restrict__ o0, float* __restrict__ o1,
    float* __restrict__ o2, float* __restrict__ o3,
    int M, int N, int K, int Kc) {
  __shared__ __align__(16) u16 As[128 * 32];
  __shared__ __align__(16) u16 Bs[128 * 32];
  int tid = threadIdx.x;
  int lane = tid & 63;
  int wave = tid >> 6;
  int quad = lane >> 4;
  int l16 = lane & 15;
  int mt, nt;
  swizzle_mn(mt, nt);
  int m0 = mt * 128;
  int n0 = nt * 128;
  int z = blockIdx.z;
  int kb = z * Kc;
  int wm = (wave >> 1) * 64;
  int wn = (wave & 1) * 64;

  f32x4 zero = {0.f, 0.f, 0.f, 0.f};
  f32x4 acc[4][4];
#pragma unroll
  for (int i = 0; i < 4; i++)
#pragma unroll
    for (int j = 0; j < 4; j++) acc[i][j] = zero;

  int c0 = tid, c1 = tid + 256;
  const u16* ga0 = A + (size_t)(m0 + (c0 >> 2)) * K + (c0 & 3) * 8 + kb;
  const u16* ga1 = A + (size_t)(m0 + (c1 >> 2)) * K + (c1 & 3) * 8 + kb;
  const u16* gb0 = BT + (size_t)(n0 + (c0 >> 2)) * K + (c0 & 3) * 8 + kb;
  const u16* gb1 = BT + (size_t)(n0 + (c1 >> 2)) * K + (c1 & 3) * 8 + kb;

  for (int k0 = 0; k0 < Kc; k0 += 32) {
    gload16(ga0 + k0, &As[c0 * 8]);
    gload16(ga1 + k0, &As[c1 * 8]);
    gload16(gb0 + k0, &Bs[c0 * 8]);
    gload16(gb1 + k0, &Bs[c1 * 8]);
    __syncthreads();
    bf16x8 af[4], bfr[4];
#pragma unroll
    for (int i = 0; i < 4; i++)
      af[i] = *(const bf16x8*)&As[(wm + i * 16 + l16) * 32 + quad * 8];
#pragma unroll
    for (int j = 0; j < 4; j++)
      bfr[j] = *(const bf16x8*)&Bs[(wn + j * 16 + l16) * 32 + quad * 8];
#pragma unroll
    for (int i = 0; i < 4; i++)
#pragma unroll
      for (int j = 0; j < 4; j++)
        acc[i][j] = mfma16(af[i], bfr[j], acc[i][j]);
    __syncthreads();
  }

  float* outz = z == 0 ? o0 : (z == 1 ? o1 : (z == 2 ? o2 : o3));
  float biasmul = (z == 0) ? 1.f : 0.f;
#pragma unroll
  for (int j = 0; j < 4; j++) {
    int gcol = n0 + wn + j * 16 + l16;
    float bv = bias[gcol] * biasmul;
#pragma unroll
    for (int i = 0; i < 4; i++) {
#pragma unroll
      for (int r = 0; r < 4; r++) {
        int grow = m0 + wm + i * 16 + quad * 4 + r;
        outz[(size_t)grow * N + gcol] = acc[i][j][r] + bv;
      }
    }
  }
}

// ---------------- fused QKV GEMM (q pre-scaled by 1/sqrt(HD)*log2e) --------
__global__ __launch_bounds__(256, 4) void gemm_qkv(
    const u16* __restrict__ A, const u16* __restrict__ BT,
    const float* __restrict__ bq, const float* __restrict__ bk,
    const float* __restrict__ bvp,
    u16* __restrict__ qb, u16* __restrict__ kb, u16* __restrict__ vb) {
  const int K = 1024;
  __shared__ __align__(16) u16 As[128 * 32];
  __shared__ __align__(16) u16 Bs[128 * 32];
  int tid = threadIdx.x;
  int lane = tid & 63;
  int wave = tid >> 6;
  int quad = lane >> 4;
  int l16 = lane & 15;
  int mt, nt;
  swizzle_mn(mt, nt);
  int m0 = mt * 128;
  int n0 = nt * 128;
  int wm = (wave >> 1) * 64;
  int wn = (wave & 1) * 64;

  f32x4 zero = {0.f, 0.f, 0.f, 0.f};
  f32x4 acc[4][4];
#pragma unroll
  for (int i = 0; i < 4; i++)
#pragma unroll
    for (int j = 0; j < 4; j++) acc[i][j] = zero;

  int c0 = tid, c1 = tid + 256;
  const u16* ga0 = A + (size_t)(m0 + (c0 >> 2)) * K + (c0 & 3) * 8;
  const u16* ga1 = A + (size_t)(m0 + (c1 >> 2)) * K + (c1 & 3) * 8;
  const u16* gb0 = BT + (size_t)(n0 + (c0 >> 2)) * K + (c0 & 3) * 8;
  const u16* gb1 = BT + (size_t)(n0 + (c1 >> 2)) * K + (c1 & 3) * 8;

  for (int k0 = 0; k0 < K; k0 += 32) {
    gload16(ga0 + k0, &As[c0 * 8]);
    gload16(ga1 + k0, &As[c1 * 8]);
    gload16(gb0 + k0, &Bs[c0 * 8]);
    gload16(gb1 + k0, &Bs[c1 * 8]);
    __syncthreads();
    bf16x8 af[4], bfr[4];
#pragma unroll
    for (int i = 0; i < 4; i++)
      af[i] = *(const bf16x8*)&As[(wm + i * 16 + l16) * 32 + quad * 8];
#pragma unroll
    for (int j = 0; j < 4; j++)
      bfr[j] = *(const bf16x8*)&Bs[(wn + j * 16 + l16) * 32 + quad * 8];
#pragma unroll
    for (int i = 0; i < 4; i++)
#pragma unroll
      for (int j = 0; j < 4; j++)
        acc[i][j] = mfma16(af[i], bfr[j], acc[i][j]);
    __syncthreads();
  }

  int region = n0 >> 10;
  const float* bias = region == 0 ? bq : (region == 1 ? bk : bvp);
  u16* outp = region == 0 ? qb : (region == 1 ? kb : vb);
  float scale = region == 0 ? 0.125f * 1.4426950408889634f : 1.f;

#pragma unroll
  for (int j = 0; j < 4; j++) {
    int gcol = (n0 & 1023) + wn + j * 16 + l16;
    float bv = bias[gcol];
    int h = gcol >> 6, hd = gcol & 63;
#pragma unroll
    for (int i = 0; i < 4; i++) {
#pragma unroll
      for (int r = 0; r < 4; r++) {
        int grow = m0 + wm + i * 16 + quad * 4 + r;
        float val = (acc[i][j][r] + bv) * scale;
        int b = grow >> 11, s = grow & 2047;
        if (region < 2) {
          outp[(((size_t)(b * H_ + h)) * S_ + s) * HD_ + hd] = f2bf(val);
        } else {
          outp[(((size_t)(b * H_ + h)) * HD_ + hd) * S_ + s] = f2bf(val);
        }
      }
    }
  }
}

// ---------------- flash attention: S^T form, P stays in registers ----------
// QK^T computed TRANSPOSED (A=K, B=Q -> C[key][q]): each lane then holds
// P^T[key=quad*4+r][q=l16], which IS the B-operand layout of the K=16 MFMA
// v_mfma_f32_16x16x16_bf16 -> PV runs directly from registers. No P LDS
// round-trip. V frags are b64 reads; l-reduce = 2 cross-quad shuffles.
// O (hd-major per lane) is transposed through the dead Ks buffer for
// coalesced global stores. Double-buffered K/V staging, 1 barrier/tile.
__global__ __launch_bounds__(256, 2) void attn_kernel(
    const u16* __restrict__ q, const u16* __restrict__ k,
    const u16* __restrict__ vt, const int* __restrict__ mask,
    u16* __restrict__ ao) {
  __shared__ __align__(16) u16 Ks[2][64 * 72];
  __shared__ __align__(16) u16 Vs[2][64 * 72];
  int tid = threadIdx.x;
  int lane = tid & 63;
  int wave = tid >> 6;
  int quad = lane >> 4;
  int l16 = lane & 15;
  int bh = blockIdx.y;
  int b = bh >> 4;
  int h = bh & 15;
  int qrow0 = blockIdx.x * 128 + wave * 32;

  const u16* qh = q + (size_t)bh * S_ * HD_;
  const u16* kh = k + (size_t)bh * S_ * HD_;
  const u16* vh = vt + (size_t)bh * HD_ * S_;

  // Q frags: B-operand (n = l16 = q-row, k = d)
  bf16x8 qfA0 = *(const bf16x8*)(qh + (size_t)(qrow0 + l16) * HD_ + quad * 8);
  bf16x8 qfA1 = *(const bf16x8*)(qh + (size_t)(qrow0 + l16) * HD_ + 32 + quad * 8);
  bf16x8 qfB0 = *(const bf16x8*)(qh + (size_t)(qrow0 + 16 + l16) * HD_ + quad * 8);
  bf16x8 qfB1 = *(const bf16x8*)(qh + (size_t)(qrow0 + 16 + l16) * HD_ + 32 + quad * 8);

  int sr = tid >> 3, sc = tid & 7;
  const u16* kg0 = kh + sr * HD_ + sc * 8;
  const u16* kg1 = kh + (sr + 32) * HD_ + sc * 8;
  const u16* vg0 = vh + (size_t)sr * S_ + sc * 8;
  const u16* vg1 = vh + (size_t)(sr + 32) * S_ + sc * 8;
  int so0 = sr * 72 + sc * 8;
  int so1 = (sr + 32) * 72 + sc * 8;

  float l_accA = 0.f, l_accB = 0.f;
  f32x4 zero = {0.f, 0.f, 0.f, 0.f};
  f32x4 o_accA[4], o_accB[4];  // [c][r]: hd = c*16 + quad*4 + r, q = l16
#pragma unroll
  for (int c = 0; c < 4; c++) { o_accA[c] = zero; o_accB[c] = zero; }

  // prologue: stage tile 0 into buf 0, prefetch tile 1 into regs
  bf16x8 kv0 = *(const bf16x8*)(kg0);
  bf16x8 kv1 = *(const bf16x8*)(kg1);
  bf16x8 vv0 = *(const bf16x8*)(vg0);
  bf16x8 vv1 = *(const bf16x8*)(vg1);
  *(bf16x8*)&Ks[0][so0] = kv0;
  *(bf16x8*)&Ks[0][so1] = kv1;
  *(bf16x8*)&Vs[0][so0] = vv0;
  *(bf16x8*)&Vs[0][so1] = vv1;
  kv0 = *(const bf16x8*)(kg0 + (size_t)64 * HD_);
  kv1 = *(const bf16x8*)(kg1 + (size_t)64 * HD_);
  vv0 = *(const bf16x8*)(vg0 + 64);
  vv1 = *(const bf16x8*)(vg1 + 64);

  const int* mrow = mask + b * S_ + quad * 4;

  int cur = 0;
  for (int kt = 0; kt < S_; kt += 64) {
    __syncthreads();  // buf[cur] staged; previous tile's compute done
    if (kt + 64 < S_) {
      int alt = cur ^ 1;
      *(bf16x8*)&Ks[alt][so0] = kv0;
      *(bf16x8*)&Ks[alt][so1] = kv1;
      *(bf16x8*)&Vs[alt][so0] = vv0;
      *(bf16x8*)&Vs[alt][so1] = vv1;
      int nk = (kt + 128) & (S_ - 1);  // wrap: harmless dummy on tail
      kv0 = *(const bf16x8*)(kg0 + (size_t)nk * HD_);
      kv1 = *(const bf16x8*)(kg1 + (size_t)nk * HD_);
      vv0 = *(const bf16x8*)(vg0 + nk);
      vv1 = *(const bf16x8*)(vg1 + nk);
    }

    const u16* ksb = &Ks[cur][0];
    const u16* vsb = &Vs[cur][0];
#pragma unroll
    for (int kg = 0; kg < 4; kg++) {
      // A = K frag (m = key-within-group = l16)
      int rowb = (kg * 16 + l16) * 72;
      bf16x8 ka0 = *(const bf16x8*)&ksb[rowb + quad * 8];
      bf16x8 ka1 = *(const bf16x8*)&ksb[rowb + 32 + quad * 8];
      f32x4 stA = mfma16(ka1, qfA1, mfma16(ka0, qfA0, zero));
      f32x4 stB = mfma16(ka1, qfB1, mfma16(ka0, qfB0, zero));
      // stX[r]: key = kt + kg*16 + quad*4 + r, q = l16
      int4 mk4 = *(const int4*)(mrow + kt + kg * 16);
      float pA0 = mk4.x ? exp2f(stA[0]) : 0.f;
      float pA1 = mk4.y ? exp2f(stA[1]) : 0.f;
      float pA2 = mk4.z ? exp2f(stA[2]) : 0.f;
      float pA3 = mk4.w ? exp2f(stA[3]) : 0.f;
      float pB0 = mk4.x ? exp2f(stB[0]) : 0.f;
      float pB1 = mk4.y ? exp2f(stB[1]) : 0.f;
      float pB2 = mk4.z ? exp2f(stB[2]) : 0.f;
      float pB3 = mk4.w ? exp2f(stB[3]) : 0.f;
      l_accA += (pA0 + pA1) + (pA2 + pA3);
      l_accB += (pB0 + pB1) + (pB2 + pB3);
      // pack P^T into K=16 B-frags (truncation pack)
      uint2 wA = { __builtin_amdgcn_perm(__float_as_uint(pA1),
                                         __float_as_uint(pA0), 0x07060302u),
                   __builtin_amdgcn_perm(__float_as_uint(pA3),
                                         __float_as_uint(pA2), 0x07060302u) };
      uint2 wB = { __builtin_amdgcn_perm(__float_as_uint(pB1),
                                         __float_as_uint(pB0), 0x07060302u),
                   __builtin_amdgcn_perm(__float_as_uint(pB3),
                                         __float_as_uint(pB2), 0x07060302u) };
      bf16x4 pfA = __builtin_bit_cast(bf16x4, wA);
      bf16x4 pfB = __builtin_bit_cast(bf16x4, wB);
#pragma unroll
      for (int c = 0; c < 4; c++) {
        bf16x4 vf = *(const bf16x4*)&vsb[(c * 16 + l16) * 72 + kg * 16 + quad * 4];
        o_accA[c] = mfma16k16(vf, pfA, o_accA[c]);
        o_accB[c] = mfma16k16(vf, pfB, o_accB[c]);
      }
    }
    cur ^= 1;
  }

  // l reduce across quads: lanes with same l16 hold partial sums
  float sA = l_accA, sB = l_accB;
  sA += __shfl_xor(sA, 16); sA += __shfl_xor(sA, 32);
  sB += __shfl_xor(sB, 16); sB += __shfl_xor(sB, 32);
  float invA = 1.f / sA, invB = 1.f / sB;

  // transpose O through dead Ks buffer for coalesced stores
  __syncthreads();  // all waves done reading Ks/Vs
  u16* scr = ((u16*)Ks) + wave * 2304;  // 32 rows x 72
#pragma unroll
  for (int c = 0; c < 4; c++) {
#pragma unroll
    for (int rp = 0; rp < 4; rp += 2) {
      float yA0 = o_accA[c][rp] * invA, yA1 = o_accA[c][rp + 1] * invA;
      float yB0 = o_accB[c][rp] * invB, yB1 = o_accB[c][rp + 1] * invB;
      unsigned wa = __builtin_amdgcn_perm(__float_as_uint(yA1),
                                          __float_as_uint(yA0), 0x07060302u);
      unsigned wb = __builtin_amdgcn_perm(__float_as_uint(yB1),
                                          __float_as_uint(yB0), 0x07060302u);
      *(unsigned*)&scr[l16 * 72 + c * 16 + quad * 4 + rp] = wa;
      *(unsigned*)&scr[(16 + l16) * 72 + c * 16 + quad * 4 + rp] = wb;
    }
  }
#pragma unroll
  for (int p = 0; p < 4; p++) {
    int row = p * 8 + (lane >> 3);
    int col = (lane & 7) * 8;
    bf16x8 val = *(const bf16x8*)&scr[row * 72 + col];
    *(bf16x8*)(ao + ((size_t)(b * S_ + qrow0 + row)) * D_ + h * HD_ + col) = val;
  }
}

// ---------------- residual (4 partials) + layernorm ----------------
__global__ __launch_bounds__(256) void ln4_kernel(
    const float* __restrict__ xa,
    const float* __restrict__ a0, const float* __restrict__ a1,
    const float* __restrict__ a2, const float* __restrict__ a3,
    const float* __restrict__ g, const float* __restrict__ be,
    float* __restrict__ outf, u16* __restrict__ outb) {
  int row = blockIdx.x;
  int tid = threadIdx.x;
  int lane = tid & 63;
  int wv = tid >> 6;
  size_t off0 = (size_t)row * D_ + tid * 4;
  const float4 a = *(const float4*)(xa + off0);
  const float4 c0 = *(const float4*)(a0 + off0);
  const float4 c1 = *(const float4*)(a1 + off0);
  const float4 c2 = *(const float4*)(a2 + off0);
  const float4 c3 = *(const float4*)(a3 + off0);
  float v0 = a.x + (c0.x + c1.x) + (c2.x + c3.x);
  float v1 = a.y + (c0.y + c1.y) + (c2.y + c3.y);
  float v2 = a.z + (c0.z + c1.z) + (c2.z + c3.z);
  float v3 = a.w + (c0.w + c1.w) + (c2.w + c3.w);
  float s = v0 + v1 + v2 + v3;
  float sq = v0 * v0 + v1 * v1 + v2 * v2 + v3 * v3;
#pragma unroll
  for (int off = 1; off < 64; off <<= 1) {
    s += __shfl_xor(s, off);
    sq += __shfl_xor(sq, off);
  }
  __shared__ float red[8];
  if (lane == 0) { red[wv] = s; red[4 + wv] = sq; }
  __syncthreads();
  s = red[0] + red[1] + red[2] + red[3];
  sq = red[4] + red[5] + red[6] + red[7];
  float mean = s * (1.f / D_);
  float var = sq * (1.f / D_) - mean * mean;
  float rstd = rsqrtf(var + 1e-5f);
  const float4 gv = *(const float4*)(g + tid * 4);
  const float4 bv = *(const float4*)(be + tid * 4);
  float y0 = (v0 - mean) * rstd * gv.x + bv.x;
  float y1 = (v1 - mean) * rstd * gv.y + bv.y;
  float y2 = (v2 - mean) * rstd * gv.z + bv.z;
  float y3 = (v3 - mean) * rstd * gv.w + bv.w;
  float4 o = {y0, y1, y2, y3};
  *(float4*)(outf + off0) = o;
  if (outb) {
    ushort4 ob = {f2bf(y0), f2bf(y1), f2bf(y2), f2bf(y3)};
    *(ushort4*)(outb + off0) = ob;
  }
}

extern "C" void kernel_launch(void* const* d_in, const int* in_sizes, int n_in,
                              void* d_out, int out_size, void* d_ws, size_t ws_size,
                              hipStream_t stream) {
  const float* x = (const float*)d_in[0];
  const int* mask = (const int*)d_in[1];
  const float* Wq = (const float*)d_in[2];
  const float* bq = (const float*)d_in[3];
  const float* Wk = (const float*)d_in[4];
  const float* bk = (const float*)d_in[5];
  const float* Wv = (const float*)d_in[6];
  const float* bv = (const float*)d_in[7];
  const float* Wo = (const float*)d_in[8];
  const float* bo = (const float*)d_in[9];
  const float* W1 = (const float*)d_in[10];
  const float* b1 = (const float*)d_in[11];
  const float* W2 = (const float*)d_in[12];
  const float* b2 = (const float*)d_in[13];
  const float* g1 = (const float*)d_in[14];
  const float* be1 = (const float*)d_in[15];
  const float* g2 = (const float*)d_in[16];
  const float* be2 = (const float*)d_in[17];

  const size_t MB = 1ull << 20;
  char* ws = (char*)d_ws;
  u16* wTq = (u16*)(ws + 0 * MB);   // [wTq;wTk;wTv] contiguous = fused QKV BT
  u16* wTk = (u16*)(ws + 2 * MB);
  u16* wTv = (u16*)(ws + 4 * MB);
  u16* wTo = (u16*)(ws + 6 * MB);
  u16* w1T = (u16*)(ws + 8 * MB);   // FF x D
  u16* w2T = (u16*)(ws + 16 * MB);  // D x FF (live through ffn2)
  u16* xb  = (u16*)(ws + 24 * MB);
  u16* qb  = (u16*)(ws + 32 * MB);
  u16* kb  = (u16*)(ws + 40 * MB);
  u16* vb  = (u16*)(ws + 48 * MB);
  u16* ao  = (u16*)(ws + 56 * MB);
  float* p0 = (float*)(ws + 64 * MB);    // proj partials (sk4): 64..128
  float* p1 = (float*)(ws + 80 * MB);
  float* p2 = (float*)(ws + 96 * MB);
  float* p3 = (float*)(ws + 112 * MB);
  float* x1f = (float*)(ws + 24 * MB);   // reuse xb+qb (dead after attn)
  u16*   x1b = (u16*)(ws + 40 * MB);     // reuse kb (dead after attn)
  u16*   h1  = (u16*)(ws + 48 * MB);     // 48..80 (vb/ao/p0 dead after LN1)
  float* f0 = (float*)(ws + 80 * MB);    // ffn2 partials (p1..p3 + weights dead)
  float* f1 = (float*)(ws + 96 * MB);
  float* f2 = (float*)(ws + 112 * MB);
  float* f3 = (float*)(ws + 0 * MB);

  prep_kernel<<<dim3(16384), dim3(256), 0, stream>>>(
      x, xb, W1, w1T, W2, w2T, Wq, Wk, Wv, Wo, wTq, wTk, wTv, wTo);

  gemm_qkv<<<dim3(32, 24), dim3(256), 0, stream>>>(xb, wTq, bq, bk, bv, qb, kb, vb);

  attn_kernel<<<dim3(S_ / 128, B_ * H_), dim3(256), 0, stream>>>(qb, kb, vb, mask, ao);

  // proj: split-K x4 (Kc=256, 1024 blocks, 4/CU)
  gemm_bt_sk4<<<dim3(32, 8, 4), dim3(256), 0, stream>>>(
      ao, wTo, bo, p0, p1, p2, p3, 4096, 1024, 1024, 256);

  ln4_kernel<<<dim3(4096), dim3(256), 0, stream>>>(
      x, p0, p1, p2, p3, g1, be1, x1f, x1b);

  gemm_bt_relu<<<dim3(32, 32), dim3(256), 0, stream>>>(x1b, w1T, b1, h1, 4096, 4096, 1024);

  // ffn2: split-K x4 (1024 blocks, 4/CU), partials f0..f3
  gemm_bt_sk4<<<dim3(32, 8, 4), dim3(256), 0, stream>>>(
      h1, w2T, b2, f0, f1, f2, f3, 4096, 1024, 4096, 1024);

  ln4_kernel<<<dim3(4096), dim3(256), 0, stream>>>(
      x1f, f0, f1, f2, f3, g2, be2, (float*)d_out, (u16*)nullptr);
}